// Round 13
// baseline (353.438 us; speedup 1.0000x reference)
//
#include <hip/hip_runtime.h>
#include <math.h>

#define B  32
#define C  256
#define HH 56
#define WW 56
#define HW 3136
#define G  8
#define CG 32
#define BG 256
#define GC 8192
#define EPSF 1e-5f

typedef __attribute__((ext_vector_type(8))) short short8;
typedef __attribute__((ext_vector_type(4))) float f32x4;

#define GLOAD16(g, l) __builtin_amdgcn_global_load_lds( \
    (const __attribute__((address_space(1))) void*)(g), \
    (__attribute__((address_space(3))) void*)(l), 16, 0, 0)

__device__ __forceinline__ float sigmoidf_(float v){ return 1.0f/(1.0f+__expf(-v)); }
__device__ __forceinline__ unsigned short f2bf(float v){
  unsigned u = __builtin_bit_cast(unsigned, v);
  u = u + 0x7FFFu + ((u>>16)&1u);
  return (unsigned short)(u>>16);
}
__device__ __forceinline__ float bf2f(unsigned short v){
  return __builtin_bit_cast(float, ((unsigned)v)<<16);
}

// kxt: x -> xt bf16 pixel-major (interior only; halo by khalo)
__global__ void kxt(const float* __restrict__ x, unsigned short* __restrict__ xt){
  int bid = blockIdx.x;
  int b = bid / 196; int r2 = bid % 196; int icb = r2 / 49; int pxb = r2 % 49;
  __shared__ float t[64][65];
  int tid = threadIdx.x;
  #pragma unroll
  for(int k=0;k<16;k++){
    int e = k*256 + tid;
    int ic = e>>6, px = e&63;
    t[ic][px] = x[((size_t)(b*256 + icb*64 + ic))*HW + pxb*64 + px];
  }
  __syncthreads();
  #pragma unroll
  for(int k=0;k<16;k++){
    int e = k*256 + tid;
    int px = e>>6, ic = e&63;
    int pxg = pxb*64 + px;
    int pi = pxg/56, pj = pxg%56;
    xt[(((size_t)b*58 + pi + 1)*58 + pj + 1)*256 + icb*64 + ic] = f2bf(t[ic][px]);
  }
}

// khalo: zero the 228 halo pixels per batch
__global__ void khalo(unsigned short* __restrict__ xt){
  int bid = blockIdx.x;            // 32*228
  int b = bid/228, hp = bid%228;
  int pi, pj;
  if(hp<58){pi=0;pj=hp;}
  else if(hp<116){pi=57;pj=hp-58;}
  else if(hp<172){pi=hp-116+1;pj=0;}
  else {pi=hp-172+1;pj=57;}
  xt[(((size_t)b*58+pi)*58+pj)*256 + threadIdx.x] = 0;
}

// K1T: row/col means from xt (thread = channel, coalesced 512B/pixel)
__global__ __launch_bounds__(256) void k1t(const unsigned short* __restrict__ xt,
    float* __restrict__ rowm, float* __restrict__ colm){
  int bid = blockIdx.x;           // 3584 = 32 b x 2 rc x 56 idx
  int b = bid / 112; int r = bid % 112; int rc = r / 56; int idx = r % 56;
  int c = threadIdx.x;
  const unsigned short* xb = xt + (size_t)b*58*58*256 + c;
  float s = 0.f;
  if(rc == 0){
    #pragma unroll 8
    for(int j=0;j<56;j++) s += bf2f(xb[((size_t)(idx+1)*58 + (j+1))*256]);
    rowm[((size_t)b*256 + c)*56 + idx] = s*(1.0f/56.0f);
  } else {
    #pragma unroll 8
    for(int i=0;i<56;i++) s += bf2f(xb[((size_t)(i+1)*58 + (idx+1))*256]);
    colm[((size_t)b*256 + c)*56 + idx] = s*(1.0f/56.0f);
  }
}

// K2: 1x1 conv on [rowmean;colmean] + sigmoid; also writes transposed tables
__global__ void k2_hw(const float* __restrict__ rowm, const float* __restrict__ colm,
                      const float* __restrict__ w1, const float* __restrict__ b1,
                      float* __restrict__ sh, float* __restrict__ sw,
                      float* __restrict__ shT, float* __restrict__ swT){
  int bg = blockIdx.x;
  int b = bg>>3, g = bg&7;
  __shared__ float inb[32][112];
  __shared__ float wt[32*32];
  __shared__ float bb[32];
  for(int idx=threadIdx.x; idx<32*56; idx+=blockDim.x){
    int ic=idx/56, p=idx%56;
    inb[ic][p]    = rowm[(bg*32+ic)*56+p];
    inb[ic][56+p] = colm[(bg*32+ic)*56+p];
  }
  for(int idx=threadIdx.x; idx<1024; idx+=blockDim.x) wt[idx]=w1[idx];
  if(threadIdx.x<32) bb[threadIdx.x]=b1[threadIdx.x];
  __syncthreads();
  for(int o=threadIdx.x; o<32*112; o+=blockDim.x){
    int oc=o/112, p=o%112;
    float s=bb[oc];
    #pragma unroll
    for(int ic=0;ic<32;ic++) s += wt[oc*32+ic]*inb[ic][p];
    float sg = sigmoidf_(s);
    int c = g*32+oc;
    if(p<56){
      sh[(bg*32+oc)*56+p]=sg;
      shT[((size_t)b*56+p)*256 + c]=sg;
    } else {
      sw[(bg*32+oc)*56+(p-56)]=sg;
      swT[((size_t)b*56+(p-56))*256 + c]=sg;
    }
  }
}

// K2b: x11 = softmax(gn_b); x11[32] = dot(x11, b3a)
__global__ void k2b_x11(const float* __restrict__ gnb, const float* __restrict__ b3a, float* __restrict__ x11){
  __shared__ float v[32];
  if(threadIdx.x<32) v[threadIdx.x]=gnb[threadIdx.x];
  __syncthreads();
  if(threadIdx.x==0){
    float m=-1e30f; for(int i=0;i<32;i++) m=fmaxf(m,v[i]);
    float s=0.f; for(int i=0;i<32;i++){ v[i]=__expf(v[i]-m); s+=v[i]; }
    float d=0.f;
    for(int i=0;i<32;i++){ float p=v[i]/s; x11[i]=p; d+=p*b3a[i]; }
    x11[32]=d;
  }
}

// K3T: per-gc sum & sumsq of x0 from xt (thread = channel)
__global__ __launch_bounds__(256) void k3t(const unsigned short* __restrict__ xt,
    const float* __restrict__ shT, const float* __restrict__ swT,
    float* __restrict__ gsum, float* __restrict__ gsq){
  int bid = blockIdx.x;     // 1792 = 32 b x 56 i
  int b = bid / 56, i = bid % 56;
  int c = threadIdx.x;
  float shv = shT[((size_t)b*56+i)*256 + c];
  const unsigned short* xb = xt + ((size_t)(b*58 + i+1)*58 + 1)*256 + c;
  const float* swp = swT + (size_t)b*56*256 + c;
  float s=0.f, s2=0.f;
  #pragma unroll 8
  for(int j=0;j<56;j++){
    float x0 = bf2f(xb[(size_t)j*256]) * shv * swp[(size_t)j*256];
    s += x0; s2 += x0*x0;
  }
  atomicAdd(&gsum[b*256+c], s);
  atomicAdd(&gsq[b*256+c], s2);
}

__global__ void k4a(const float* __restrict__ gsum, const float* __restrict__ gsq,
                    float* __restrict__ mu, float* __restrict__ istd){
  int gc=blockIdx.x*256+threadIdx.x;
  float m=gsum[gc]*(1.0f/HW);
  float v=gsq[gc]*(1.0f/HW)-m*m;
  mu[gc]=m; istd[gc]=rsqrtf(v+EPSF);
}

__global__ void k4b(const float* __restrict__ gsum, const float* __restrict__ gsq,
                    float* __restrict__ bm, float* __restrict__ binv){
  int c=threadIdx.x;
  float s=0.f,s2=0.f;
  for(int b=0;b<B;b++){ s+=gsum[b*256+c]; s2+=gsq[b*256+c]; }
  float m=s*(1.0f/(B*HW));
  float v=s2*(1.0f/(B*HW))-m*m;
  bm[c]=m; binv[c]=rsqrtf(v+EPSF);
}

// K5M: grouped 3x3 conv (32->32 per bg) via bf16 MFMA implicit GEMM.
__global__ __launch_bounds__(128) void k5m(const unsigned short* __restrict__ xt,
    const unsigned short* __restrict__ wta, const float* __restrict__ x11,
    float* __restrict__ w1a, float* __restrict__ cs2){
  __shared__ short Bs[6*58*32];
  int bid = blockIdx.x;              // 3584 = 8 xcd x 4 b x 8 g x 14 pt
  int xcd = bid & 7; int idx = bid >> 3;
  int b = xcd + 8*(idx/112); int idx2 = idx % 112;
  int g = idx2 / 14; int pt = idx2 % 14;
  int bg = b*8 + g;
  int i0 = pt*4;
  int tid = threadIdx.x;
  int lane = tid & 63, wv = tid >> 6;
  int q = lane >> 4, rl = lane & 15;
  const unsigned short* xb = xt + (size_t)b*58*58*256 + g*32;

  #pragma unroll
  for(int issue=0; issue<11; ++issue){
    int idxl = issue*128 + tid;
    if(idxl < 1392){
      int pl = idxl >> 2, ch = idxl & 3;
      int r = pl / 58, jj = pl - r*58;
      const unsigned short* src = xb + ((size_t)(i0 + r)*58 + jj)*256 + ((ch ^ ((pl>>1)&3))<<3);
      GLOAD16(src, &Bs[idxl*8]);
    }
  }
  __syncthreads();

  f32x4 acc[2][7];
  #pragma unroll
  for(int mi=0;mi<2;mi++)
    #pragma unroll
    for(int ni=0;ni<7;ni++) acc[mi][ni]=(f32x4){0.f,0.f,0.f,0.f};

  int pr[7], pj[7];
  #pragma unroll
  for(int ni=0;ni<7;ni++){
    int px = wv*112 + ni*16 + rl;
    pr[ni] = px/56; pj[ni] = px - pr[ni]*56;
  }

  for(int tap=0; tap<9; ++tap){
    int dy = tap/3, dx = tap - dy*3;
    short8 a[2], bfr[7];
    #pragma unroll
    for(int mi=0;mi<2;mi++)
      a[mi] = *(const short8*)(wta + tap*1024 + (mi*16+rl)*32 + q*8);
    #pragma unroll
    for(int ni=0;ni<7;ni++){
      int pix = (pr[ni] + dy)*58 + pj[ni] + dx;
      int cs = q ^ ((pix>>1)&3);
      bfr[ni] = *(const short8*)&Bs[pix*32 + cs*8];
    }
    #pragma unroll
    for(int mi=0;mi<2;mi++)
      #pragma unroll
      for(int ni=0;ni<7;ni++)
        acc[mi][ni] = __builtin_amdgcn_mfma_f32_16x16x32_bf16(a[mi], bfr[ni], acc[mi][ni], 0,0,0);
  }

  float x11v[2][4];
  #pragma unroll
  for(int mi=0;mi<2;mi++)
    #pragma unroll
    for(int r=0;r<4;r++) x11v[mi][r] = x11[mi*16 + q*4 + r];
  float x11b = x11[32];
  size_t pxg0 = (size_t)bg*HW + i0*56 + wv*112;
  #pragma unroll
  for(int ni=0;ni<7;ni++){
    float s=0.f;
    #pragma unroll
    for(int mi=0;mi<2;mi++)
      #pragma unroll
      for(int r=0;r<4;r++) s += x11v[mi][r]*acc[mi][ni][r];
    s += __shfl_xor(s,16,64);
    s += __shfl_xor(s,32,64);
    if(lane<16) w1a[pxg0 + ni*16 + lane] = s + x11b;
  }
  #pragma unroll
  for(int mi=0;mi<2;mi++){
    #pragma unroll
    for(int r=0;r<4;r++){
      float s=0.f;
      #pragma unroll
      for(int ni=0;ni<7;ni++) s += acc[mi][ni][r];
      s += __shfl_xor(s,1,64);
      s += __shfl_xor(s,2,64);
      s += __shfl_xor(s,4,64);
      s += __shfl_xor(s,8,64);
      if(rl==0) atomicAdd(&cs2[bg*32 + mi*16 + q*4 + r], s);
    }
  }
}

// K6: per-bg softmax over x2 channel means -> a[gc], cst[bg]
__global__ void k6(const float* __restrict__ cs2, const float* __restrict__ b3a,
                   const float* __restrict__ mu, const float* __restrict__ istd,
                   const float* __restrict__ gnw, const float* __restrict__ gnb,
                   float* __restrict__ av, float* __restrict__ cst){
  int bg=blockIdx.x; int t=threadIdx.x; // 32 threads
  float m = cs2[bg*32+t]*(1.0f/HW) + b3a[t];
  float mx=m;
  for(int off=16;off>0;off>>=1) mx=fmaxf(mx,__shfl_xor(mx,off,32));
  float e=__expf(m-mx);
  float s=e;
  for(int off=16;off>0;off>>=1) s+=__shfl_xor(s,off,32);
  float x21=e/s;
  int gc=bg*32+t;
  float is=istd[gc];
  av[gc]=x21*is*gnw[t];
  float cv=x21*(gnb[t]-mu[gc]*is*gnw[t]);
  for(int off=16;off>0;off>>=1) cv+=__shfl_xor(cv,off,32);
  if(t==0) cst[bg]=cv;
}

// K7X: pixel-major k7 using xt
__global__ __launch_bounds__(256) void k7x(const unsigned short* __restrict__ xt,
    const float* __restrict__ shT, const float* __restrict__ swT,
    const float* __restrict__ av, const float* __restrict__ binv, const float* __restrict__ cst,
    const float* __restrict__ w1a, float* __restrict__ sg1, float* __restrict__ s3pre){
  int bid = blockIdx.x; int b = bid/56, i = bid%56;
  __shared__ float shs[256], avs[256], bins[256], cst8[8];
  int tid = threadIdx.x;
  shs[tid]  = shT[((size_t)b*56+i)*256 + tid];
  avs[tid]  = av[b*256 + tid];
  bins[tid] = binv[tid];
  if(tid<8) cst8[tid] = cst[b*8+tid];
  __syncthreads();
  int h = tid>>5, l = tid&31;
  int bg = l>>2;
  int c0 = l*8;
  float sh8[8], av8[8], bi8[8];
  #pragma unroll
  for(int m=0;m<8;m++){ sh8[m]=shs[c0+m]; av8[m]=avs[c0+m]; bi8[m]=bins[c0+m]; }
  float cstv = cst8[bg];
  for(int pass=0; pass<7; ++pass){
    int j = pass*8 + h;
    short8 xv = *(const short8*)(xt + (((size_t)b*58 + i+1)*58 + j+1)*256 + c0);
    const float* swp = swT + ((size_t)b*56 + j)*256 + c0;
    float ws=0.f, s3=0.f;
    #pragma unroll
    for(int m=0;m<8;m++){
      float x0 = bf2f((unsigned short)xv[m]) * sh8[m] * swp[m];
      ws += av8[m]*x0;
      s3 += bi8[m]*x0;
    }
    ws += __shfl_xor(ws,1,64);
    ws += __shfl_xor(ws,2,64);
    s3 += __shfl_xor(s3,1,64);
    s3 += __shfl_xor(s3,2,64);
    s3 += __shfl_xor(s3,4,64);
    s3 += __shfl_xor(s3,8,64);
    s3 += __shfl_xor(s3,16,64);
    int p = i*56 + j;
    if((l&3)==0){
      size_t o = ((size_t)(b*8+bg))*HW + p;
      sg1[o] = sigmoidf_(w1a[o] + ws + cstv);
    }
    if(l==0) s3pre[(size_t)b*HW + p] = s3*(1.0f/256.0f);
  }
}

// softmax over HW per b, with input scale (512 threads)
__global__ void k_softmax_hw(const float* __restrict__ in, float* __restrict__ out, float scale){
  int b=blockIdx.x;
  const float* ip=in+(size_t)b*HW;
  float mx=-1e30f;
  for(int p=threadIdx.x;p<HW;p+=blockDim.x) mx=fmaxf(mx,ip[p]*scale);
  for(int off=32;off>0;off>>=1) mx=fmaxf(mx,__shfl_xor(mx,off,64));
  __shared__ float red[8];
  int wid=threadIdx.x>>6, lane=threadIdx.x&63;
  if(lane==0) red[wid]=mx;
  __syncthreads();
  mx=red[0];
  #pragma unroll
  for(int w=1;w<8;w++) mx=fmaxf(mx,red[w]);
  float s=0.f;
  for(int p=threadIdx.x;p<HW;p+=blockDim.x) s+=__expf(ip[p]*scale-mx);
  for(int off=32;off>0;off>>=1) s+=__shfl_down(s,off,64);
  __shared__ float red2[8];
  if(lane==0) red2[wid]=s;
  __syncthreads();
  s=red2[0];
  #pragma unroll
  for(int w=1;w<8;w++) s+=red2[w];
  float inv=1.0f/s;
  for(int p=threadIdx.x;p<HW;p+=blockDim.x) out[(size_t)b*HW+p]=__expf(ip[p]*scale-mx)*inv;
}

// wt transform: wt[tap][oc][ic] = bf16(w3b[oc][ic][tap])
__global__ void kwt(const float* __restrict__ w3b, unsigned short* __restrict__ wt){
  int idx = blockIdx.x*256 + threadIdx.x;
  int tap = idx >> 16; int r = idx & 65535; int oc = r >> 8; int ic = r & 255;
  wt[idx] = f2bf(w3b[((size_t)oc*256 + ic)*9 + tap]);
}

// wta transform: wta[tap][oc][ic] = bf16(w3a[oc][ic][tap])
__global__ void kwta(const float* __restrict__ w3a, unsigned short* __restrict__ wta){
  int idx = blockIdx.x*256 + threadIdx.x;
  if(idx < 9216){
    int tap = idx >> 10; int r = idx & 1023; int oc = r >> 5; int ic = r & 31;
    wta[idx] = f2bf(w3a[((size_t)oc*32 + ic)*9 + tap]);
  }
}

// K9M: 256->256 3x3 conv via bf16 MFMA implicit GEMM, fused reductions.
// T3/T4 retrofit: TRIPLE-buffered LDS, 3-tile-deep prefetch, counted vmcnt
// (never drains to 0 in steady state), raw READY/FREE barriers with
// sched_barrier(0) pins. XCD-aware bid swizzle unchanged.
__global__ __launch_bounds__(512) void k9m(const unsigned short* __restrict__ xt,
    const unsigned short* __restrict__ wt, const float* __restrict__ x31,
    float* __restrict__ s4pre, float* __restrict__ w2a){
  __shared__ short Ab[3][128*32];
  __shared__ short Bb[3][224*32];
  int bid = blockIdx.x;              // 896 = 8 xcd x 4 b x 28 rr
  int xcd = bid & 7; int idx = bid >> 3;
  int b = xcd + 8*(idx/28); int rr = idx % 28;
  int pt = rr >> 1; int oct = rr & 1;
  int i0 = pt*4; int ocb = oct*128;
  int tid = threadIdx.x;
  int lane = tid & 63, wv = tid >> 6;
  int wm = wv & 3, wn = wv >> 2;
  int q = lane >> 4, rl = lane & 15;
  const unsigned short* xb = xt + (size_t)b*58*58*256;

  // Per-thread loads per STAGE: 3 for tid<384, 2 for tid>=384 (wave-uniform).
  #define STAGE(BUF, T) do{ \
    int tap_ = (T) >> 3; int ic0_ = ((T) & 7) << 5; \
    { int idxl = tid; int oc_ = idxl>>2, cs_ = idxl&3; \
      const unsigned short* src = wt + (((size_t)tap_*256 + ocb + oc_)*256 + ic0_ + (((cs_ ^ ((oc_>>1)&3)))<<3)); \
      GLOAD16(src, &Ab[BUF][idxl*8]); } \
    int dy_ = tap_/3, dx_ = tap_%3; \
    { int idxl = tid; int px_ = idxl>>2, cs_ = idxl&3; int r_ = px_/56, j_ = px_ - r_*56; \
      const unsigned short* src = xb + ((size_t)((i0 + r_ + dy_)*58 + (j_ + dx_)))*256 + ic0_ + ((cs_ ^ ((px_>>1)&3))<<3); \
      GLOAD16(src, &Bb[BUF][idxl*8]); } \
    if(tid < 384){ int idxl = tid + 512; int px_ = idxl>>2, cs_ = idxl&3; int r_ = px_/56, j_ = px_ - r_*56; \
      const unsigned short* src = xb + ((size_t)((i0 + r_ + dy_)*58 + (j_ + dx_)))*256 + ic0_ + ((cs_ ^ ((px_>>1)&3))<<3); \
      GLOAD16(src, &Bb[BUF][idxl*8]); } }while(0)

  STAGE(0, 0);
  STAGE(1, 1);
  STAGE(2, 2);

  f32x4 acc[2][7];
  #pragma unroll
  for(int mi=0;mi<2;mi++)
    #pragma unroll
    for(int ni=0;ni<7;ni++) acc[mi][ni] = (f32x4){0.f,0.f,0.f,0.f};

  int cur = 0;
  for(int t=0; t<72; ++t){
    // counted wait: tiles t+1,t+2 may stay in flight (2 stages x L loads)
    if(t <= 69){
      if(tid < 384) asm volatile("s_waitcnt vmcnt(6)" ::: "memory");
      else          asm volatile("s_waitcnt vmcnt(4)" ::: "memory");
    } else if(t == 70){
      if(tid < 384) asm volatile("s_waitcnt vmcnt(3)" ::: "memory");
      else          asm volatile("s_waitcnt vmcnt(2)" ::: "memory");
    } else {
      asm volatile("s_waitcnt vmcnt(0)" ::: "memory");
    }
    __builtin_amdgcn_s_barrier();          // READY: tile t landed for all waves
    __builtin_amdgcn_sched_barrier(0);
    short8 a[2], bf[7];
    #pragma unroll
    for(int mi=0;mi<2;mi++){
      int row = wm*32 + mi*16 + rl;
      int cs = q ^ ((row>>1)&3);
      a[mi] = *(const short8*)&Ab[cur][row*32 + cs*8];
    }
    #pragma unroll
    for(int ni=0;ni<7;ni++){
      int px = wn*112 + ni*16 + rl;
      int cs = q ^ ((px>>1)&3);
      bf[ni] = *(const short8*)&Bb[cur][px*32 + cs*8];
    }
    #pragma unroll
    for(int mi=0;mi<2;mi++)
      #pragma unroll
      for(int ni=0;ni<7;ni++)
        acc[mi][ni] = __builtin_amdgcn_mfma_f32_16x16x32_bf16(a[mi], bf[ni], acc[mi][ni], 0,0,0);
    __builtin_amdgcn_sched_barrier(0);
    __builtin_amdgcn_s_barrier();          // FREE: all waves done reading buf[cur]
    if(t+3 < 72) STAGE(cur, t+3);          // overwrite just-freed buffer
    cur = (cur==2) ? 0 : cur+1;
  }
  #undef STAGE

  size_t pxbase = (size_t)b*HW + i0*56 + wn*112;
  #pragma unroll
  for(int ni=0;ni<7;ni++){
    float s = 0.f;
    #pragma unroll
    for(int mi=0;mi<2;mi++){
      s += acc[mi][ni][0]+acc[mi][ni][1]+acc[mi][ni][2]+acc[mi][ni][3];
    }
    s += __shfl_xor(s, 16, 64);
    s += __shfl_xor(s, 32, 64);
    if(lane < 16) atomicAdd(&s4pre[pxbase + ni*16 + lane], s);
  }
  float x31v[7];
  #pragma unroll
  for(int ni=0;ni<7;ni++) x31v[ni] = x31[pxbase + ni*16 + rl];
  #pragma unroll
  for(int mi=0;mi<2;mi++){
    #pragma unroll
    for(int r=0;r<4;r++){
      float s = 0.f;
      #pragma unroll
      for(int ni=0;ni<7;ni++) s += x31v[ni]*acc[mi][ni][r];
      s += __shfl_xor(s, 1, 64);
      s += __shfl_xor(s, 2, 64);
      s += __shfl_xor(s, 4, 64);
      s += __shfl_xor(s, 8, 64);
      if(rl == 0) atomicAdd(&w2a[b*256 + ocb + wm*32 + mi*16 + q*4 + r], s);
    }
  }
}

// K11F: fused k11+k12.
__global__ __launch_bounds__(256) void k11f(const float* __restrict__ x, const float* __restrict__ sh,
    const float* __restrict__ sw, const float* __restrict__ x41, const float* __restrict__ bm,
    const float* __restrict__ binv, const float* __restrict__ w2a, const float* __restrict__ b3b,
    const float* __restrict__ sg1, float* __restrict__ out){
  int gc=blockIdx.x; int b=gc>>8, c=gc&255, bg=gc>>5;
  __shared__ float xs[HW];
  __shared__ float ssh[56], ssw[56];
  __shared__ float red[4];
  int tid=threadIdx.x;
  if(tid<56) ssh[tid]=sh[gc*56+tid];
  else if(tid>=64&&tid<120) ssw[tid-64]=sw[gc*56+tid-64];
  const float* xp=x+(size_t)gc*HW;
  const float* wp=x41+(size_t)b*HW;
  for(int p=tid;p<HW;p+=256) xs[p]=xp[p];
  __syncthreads();
  float s=0.f;
  for(int p=tid;p<HW;p+=256){
    float x0=xs[p]*ssh[p/56]*ssw[p%56];
    s+=wp[p]*x0;
  }
  for(int off=32;off>0;off>>=1) s+=__shfl_down(s,off,64);
  int wid=tid>>6, lane=tid&63;
  if(lane==0) red[wid]=s;
  __syncthreads();
  float t=red[0]+red[1]+red[2]+red[3];
  float sg2=sigmoidf_(w2a[gc]+b3b[c]+binv[c]*t-bm[c]*binv[c]);
  const float* sp=sg1+(size_t)bg*HW;
  float* op=out+(size_t)gc*HW;
  for(int p=tid;p<HW;p+=256){
    op[p]=xs[p]*(sp[p]+sg2);
  }
}

extern "C" void kernel_launch(void* const* d_in, const int* in_sizes, int n_in,
                              void* d_out, int out_size, void* d_ws, size_t ws_size,
                              hipStream_t stream) {
  const float* x   = (const float*)d_in[0];
  const float* w1  = (const float*)d_in[1];
  const float* b1  = (const float*)d_in[2];
  const float* w3a = (const float*)d_in[3];
  const float* b3a = (const float*)d_in[4];
  const float* w3b = (const float*)d_in[5];
  const float* b3b = (const float*)d_in[6];
  const float* gnw = (const float*)d_in[7];
  const float* gnb = (const float*)d_in[8];
  float* out=(float*)d_out;
  float* ws=(float*)d_ws;

  float* rowm=ws;              // 458752
  float* colm=rowm+458752;     // 458752
  float* sh  =colm+458752;     // 458752
  float* sw  =sh+458752;       // 458752
  float* x11 =sw+458752;       // 64 (33 used)
  float* gsum=x11+64;          // 8192
  float* gsq =gsum+8192;       // 8192
  float* mu  =gsq+8192;        // 8192
  float* istd=mu+8192;         // 8192
  float* bm  =istd+8192;       // 256
  float* binv=bm+256;          // 256
  float* cs2 =binv+256;        // 8192
  float* w1a =cs2+8192;        // 802816
  float* av  =w1a+802816;      // 8192
  float* cst =av+8192;         // 256
  float* s3  =cst+256;         // 100352
  float* x31 =s3+100352;       // 100352
  float* s4  =x31+100352;      // 100352
  float* x41 =s4+100352;       // 100352
  float* w2a =x41+100352;      // 8192
  float* shT =w2a+8192;        // 458752
  float* swT =shT+458752;      // 458752
  float* sg1 =swT+458752;      // 802816 (sigmoid(weights1))
  unsigned short* xt = (unsigned short*)(sg1 + 802816);  // 32*58*58*256 bf16
  unsigned short* wtb = xt + (size_t)32*58*58*256;       // 589824
  unsigned short* wta = wtb + 589824;                    // 9216

  kxt<<<32*4*49,256,0,stream>>>(x, xt);
  khalo<<<32*228,256,0,stream>>>(xt);
  kwt<<<2304,256,0,stream>>>(w3b, wtb);
  kwta<<<36,256,0,stream>>>(w3a, wta);

  k1t<<<32*112,256,0,stream>>>(xt,rowm,colm);
  k2_hw<<<BG,128,0,stream>>>(rowm,colm,w1,b1,sh,sw,shT,swT);
  k2b_x11<<<1,32,0,stream>>>(gnb,b3a,x11);
  hipMemsetAsync(gsum,0,2*8192*sizeof(float),stream);
  k3t<<<32*56,256,0,stream>>>(xt,shT,swT,gsum,gsq);
  k4a<<<32,256,0,stream>>>(gsum,gsq,mu,istd);
  k4b<<<1,256,0,stream>>>(gsum,gsq,bm,binv);
  hipMemsetAsync(cs2,0,8192*sizeof(float),stream);
  k5m<<<256*14,128,0,stream>>>(xt,wta,x11,w1a,cs2);
  k6<<<BG,32,0,stream>>>(cs2,b3a,mu,istd,gnw,gnb,av,cst);
  k7x<<<B*56,256,0,stream>>>(xt,shT,swT,av,binv,cst,w1a,sg1,s3);
  k_softmax_hw<<<B,512,0,stream>>>(s3,x31,1.0f);
  hipMemsetAsync(w2a,0,8192*sizeof(float),stream);
  hipMemsetAsync(s4,0,(size_t)HW*B*sizeof(float),stream);
  k9m<<<32*28,512,0,stream>>>(xt,wtb,x31,s4,w2a);
  k_softmax_hw<<<B,512,0,stream>>>(s4,x41,1.0f/256.0f);
  k11f<<<GC,256,0,stream>>>(x,sh,sw,x41,bm,binv,w2a,b3b,sg1,out);
}

// Round 14
// 349.470 us; speedup vs baseline: 1.0114x; 1.0114x over previous
//
#include <hip/hip_runtime.h>
#include <math.h>

#define B  32
#define C  256
#define HH 56
#define WW 56
#define HW 3136
#define G  8
#define CG 32
#define BG 256
#define GC 8192
#define EPSF 1e-5f

typedef __attribute__((ext_vector_type(8))) short short8;
typedef __attribute__((ext_vector_type(4))) float f32x4;

#define GLOAD16(g, l) __builtin_amdgcn_global_load_lds( \
    (const __attribute__((address_space(1))) void*)(g), \
    (__attribute__((address_space(3))) void*)(l), 16, 0, 0)

__device__ __forceinline__ float sigmoidf_(float v){ return 1.0f/(1.0f+__expf(-v)); }
__device__ __forceinline__ unsigned short f2bf(float v){
  unsigned u = __builtin_bit_cast(unsigned, v);
  u = u + 0x7FFFu + ((u>>16)&1u);
  return (unsigned short)(u>>16);
}
__device__ __forceinline__ float bf2f(unsigned short v){
  return __builtin_bit_cast(float, ((unsigned)v)<<16);
}

// kxt: x -> xt bf16 pixel-major (interior only; halo by khalo)
__global__ void kxt(const float* __restrict__ x, unsigned short* __restrict__ xt){
  int bid = blockIdx.x;
  int b = bid / 196; int r2 = bid % 196; int icb = r2 / 49; int pxb = r2 % 49;
  __shared__ float t[64][65];
  int tid = threadIdx.x;
  #pragma unroll
  for(int k=0;k<16;k++){
    int e = k*256 + tid;
    int ic = e>>6, px = e&63;
    t[ic][px] = x[((size_t)(b*256 + icb*64 + ic))*HW + pxb*64 + px];
  }
  __syncthreads();
  #pragma unroll
  for(int k=0;k<16;k++){
    int e = k*256 + tid;
    int px = e>>6, ic = e&63;
    int pxg = pxb*64 + px;
    int pi = pxg/56, pj = pxg%56;
    xt[(((size_t)b*58 + pi + 1)*58 + pj + 1)*256 + icb*64 + ic] = f2bf(t[ic][px]);
  }
}

// khalo: zero the 228 halo pixels per batch
__global__ void khalo(unsigned short* __restrict__ xt){
  int bid = blockIdx.x;            // 32*228
  int b = bid/228, hp = bid%228;
  int pi, pj;
  if(hp<58){pi=0;pj=hp;}
  else if(hp<116){pi=57;pj=hp-58;}
  else if(hp<172){pi=hp-116+1;pj=0;}
  else {pi=hp-172+1;pj=57;}
  xt[(((size_t)b*58+pi)*58+pj)*256 + threadIdx.x] = 0;
}

// K1T: row/col means from xt (thread = channel, coalesced 512B/pixel)
__global__ __launch_bounds__(256) void k1t(const unsigned short* __restrict__ xt,
    float* __restrict__ rowm, float* __restrict__ colm){
  int bid = blockIdx.x;           // 3584 = 32 b x 2 rc x 56 idx
  int b = bid / 112; int r = bid % 112; int rc = r / 56; int idx = r % 56;
  int c = threadIdx.x;
  const unsigned short* xb = xt + (size_t)b*58*58*256 + c;
  float s = 0.f;
  if(rc == 0){
    #pragma unroll 8
    for(int j=0;j<56;j++) s += bf2f(xb[((size_t)(idx+1)*58 + (j+1))*256]);
    rowm[((size_t)b*256 + c)*56 + idx] = s*(1.0f/56.0f);
  } else {
    #pragma unroll 8
    for(int i=0;i<56;i++) s += bf2f(xb[((size_t)(i+1)*58 + (idx+1))*256]);
    colm[((size_t)b*256 + c)*56 + idx] = s*(1.0f/56.0f);
  }
}

// K2: 1x1 conv on [rowmean;colmean] + sigmoid; also writes transposed tables
__global__ void k2_hw(const float* __restrict__ rowm, const float* __restrict__ colm,
                      const float* __restrict__ w1, const float* __restrict__ b1,
                      float* __restrict__ sh, float* __restrict__ sw,
                      float* __restrict__ shT, float* __restrict__ swT){
  int bg = blockIdx.x;
  int b = bg>>3, g = bg&7;
  __shared__ float inb[32][112];
  __shared__ float wt[32*32];
  __shared__ float bb[32];
  for(int idx=threadIdx.x; idx<32*56; idx+=blockDim.x){
    int ic=idx/56, p=idx%56;
    inb[ic][p]    = rowm[(bg*32+ic)*56+p];
    inb[ic][56+p] = colm[(bg*32+ic)*56+p];
  }
  for(int idx=threadIdx.x; idx<1024; idx+=blockDim.x) wt[idx]=w1[idx];
  if(threadIdx.x<32) bb[threadIdx.x]=b1[threadIdx.x];
  __syncthreads();
  for(int o=threadIdx.x; o<32*112; o+=blockDim.x){
    int oc=o/112, p=o%112;
    float s=bb[oc];
    #pragma unroll
    for(int ic=0;ic<32;ic++) s += wt[oc*32+ic]*inb[ic][p];
    float sg = sigmoidf_(s);
    int c = g*32+oc;
    if(p<56){
      sh[(bg*32+oc)*56+p]=sg;
      shT[((size_t)b*56+p)*256 + c]=sg;
    } else {
      sw[(bg*32+oc)*56+(p-56)]=sg;
      swT[((size_t)b*56+(p-56))*256 + c]=sg;
    }
  }
}

// K2b: x11 = softmax(gn_b); x11[32] = dot(x11, b3a)
__global__ void k2b_x11(const float* __restrict__ gnb, const float* __restrict__ b3a, float* __restrict__ x11){
  __shared__ float v[32];
  if(threadIdx.x<32) v[threadIdx.x]=gnb[threadIdx.x];
  __syncthreads();
  if(threadIdx.x==0){
    float m=-1e30f; for(int i=0;i<32;i++) m=fmaxf(m,v[i]);
    float s=0.f; for(int i=0;i<32;i++){ v[i]=__expf(v[i]-m); s+=v[i]; }
    float d=0.f;
    for(int i=0;i<32;i++){ float p=v[i]/s; x11[i]=p; d+=p*b3a[i]; }
    x11[32]=d;
  }
}

// K3T: per-gc sum & sumsq of x0 from xt (thread = channel)
__global__ __launch_bounds__(256) void k3t(const unsigned short* __restrict__ xt,
    const float* __restrict__ shT, const float* __restrict__ swT,
    float* __restrict__ gsum, float* __restrict__ gsq){
  int bid = blockIdx.x;     // 1792 = 32 b x 56 i
  int b = bid / 56, i = bid % 56;
  int c = threadIdx.x;
  float shv = shT[((size_t)b*56+i)*256 + c];
  const unsigned short* xb = xt + ((size_t)(b*58 + i+1)*58 + 1)*256 + c;
  const float* swp = swT + (size_t)b*56*256 + c;
  float s=0.f, s2=0.f;
  #pragma unroll 8
  for(int j=0;j<56;j++){
    float x0 = bf2f(xb[(size_t)j*256]) * shv * swp[(size_t)j*256];
    s += x0; s2 += x0*x0;
  }
  atomicAdd(&gsum[b*256+c], s);
  atomicAdd(&gsq[b*256+c], s2);
}

__global__ void k4a(const float* __restrict__ gsum, const float* __restrict__ gsq,
                    float* __restrict__ mu, float* __restrict__ istd){
  int gc=blockIdx.x*256+threadIdx.x;
  float m=gsum[gc]*(1.0f/HW);
  float v=gsq[gc]*(1.0f/HW)-m*m;
  mu[gc]=m; istd[gc]=rsqrtf(v+EPSF);
}

__global__ void k4b(const float* __restrict__ gsum, const float* __restrict__ gsq,
                    float* __restrict__ bm, float* __restrict__ binv){
  int c=threadIdx.x;
  float s=0.f,s2=0.f;
  for(int b=0;b<B;b++){ s+=gsum[b*256+c]; s2+=gsq[b*256+c]; }
  float m=s*(1.0f/(B*HW));
  float v=s2*(1.0f/(B*HW))-m*m;
  bm[c]=m; binv[c]=rsqrtf(v+EPSF);
}

// K5M: grouped 3x3 conv (32->32 per bg) via bf16 MFMA implicit GEMM.
__global__ __launch_bounds__(128) void k5m(const unsigned short* __restrict__ xt,
    const unsigned short* __restrict__ wta, const float* __restrict__ x11,
    float* __restrict__ w1a, float* __restrict__ cs2){
  __shared__ short Bs[6*58*32];
  int bid = blockIdx.x;              // 3584 = 8 xcd x 4 b x 8 g x 14 pt
  int xcd = bid & 7; int idx = bid >> 3;
  int b = xcd + 8*(idx/112); int idx2 = idx % 112;
  int g = idx2 / 14; int pt = idx2 % 14;
  int bg = b*8 + g;
  int i0 = pt*4;
  int tid = threadIdx.x;
  int lane = tid & 63, wv = tid >> 6;
  int q = lane >> 4, rl = lane & 15;
  const unsigned short* xb = xt + (size_t)b*58*58*256 + g*32;

  #pragma unroll
  for(int issue=0; issue<11; ++issue){
    int idxl = issue*128 + tid;
    if(idxl < 1392){
      int pl = idxl >> 2, ch = idxl & 3;
      int r = pl / 58, jj = pl - r*58;
      const unsigned short* src = xb + ((size_t)(i0 + r)*58 + jj)*256 + ((ch ^ ((pl>>1)&3))<<3);
      GLOAD16(src, &Bs[idxl*8]);
    }
  }
  __syncthreads();

  f32x4 acc[2][7];
  #pragma unroll
  for(int mi=0;mi<2;mi++)
    #pragma unroll
    for(int ni=0;ni<7;ni++) acc[mi][ni]=(f32x4){0.f,0.f,0.f,0.f};

  int pr[7], pj[7];
  #pragma unroll
  for(int ni=0;ni<7;ni++){
    int px = wv*112 + ni*16 + rl;
    pr[ni] = px/56; pj[ni] = px - pr[ni]*56;
  }

  for(int tap=0; tap<9; ++tap){
    int dy = tap/3, dx = tap - dy*3;
    short8 a[2], bfr[7];
    #pragma unroll
    for(int mi=0;mi<2;mi++)
      a[mi] = *(const short8*)(wta + tap*1024 + (mi*16+rl)*32 + q*8);
    #pragma unroll
    for(int ni=0;ni<7;ni++){
      int pix = (pr[ni] + dy)*58 + pj[ni] + dx;
      int cs = q ^ ((pix>>1)&3);
      bfr[ni] = *(const short8*)&Bs[pix*32 + cs*8];
    }
    #pragma unroll
    for(int mi=0;mi<2;mi++)
      #pragma unroll
      for(int ni=0;ni<7;ni++)
        acc[mi][ni] = __builtin_amdgcn_mfma_f32_16x16x32_bf16(a[mi], bfr[ni], acc[mi][ni], 0,0,0);
  }

  float x11v[2][4];
  #pragma unroll
  for(int mi=0;mi<2;mi++)
    #pragma unroll
    for(int r=0;r<4;r++) x11v[mi][r] = x11[mi*16 + q*4 + r];
  float x11b = x11[32];
  size_t pxg0 = (size_t)bg*HW + i0*56 + wv*112;
  #pragma unroll
  for(int ni=0;ni<7;ni++){
    float s=0.f;
    #pragma unroll
    for(int mi=0;mi<2;mi++)
      #pragma unroll
      for(int r=0;r<4;r++) s += x11v[mi][r]*acc[mi][ni][r];
    s += __shfl_xor(s,16,64);
    s += __shfl_xor(s,32,64);
    if(lane<16) w1a[pxg0 + ni*16 + lane] = s + x11b;
  }
  #pragma unroll
  for(int mi=0;mi<2;mi++){
    #pragma unroll
    for(int r=0;r<4;r++){
      float s=0.f;
      #pragma unroll
      for(int ni=0;ni<7;ni++) s += acc[mi][ni][r];
      s += __shfl_xor(s,1,64);
      s += __shfl_xor(s,2,64);
      s += __shfl_xor(s,4,64);
      s += __shfl_xor(s,8,64);
      if(rl==0) atomicAdd(&cs2[bg*32 + mi*16 + q*4 + r], s);
    }
  }
}

// K6: per-bg softmax over x2 channel means -> a[gc], cst[bg]
__global__ void k6(const float* __restrict__ cs2, const float* __restrict__ b3a,
                   const float* __restrict__ mu, const float* __restrict__ istd,
                   const float* __restrict__ gnw, const float* __restrict__ gnb,
                   float* __restrict__ av, float* __restrict__ cst){
  int bg=blockIdx.x; int t=threadIdx.x; // 32 threads
  float m = cs2[bg*32+t]*(1.0f/HW) + b3a[t];
  float mx=m;
  for(int off=16;off>0;off>>=1) mx=fmaxf(mx,__shfl_xor(mx,off,32));
  float e=__expf(m-mx);
  float s=e;
  for(int off=16;off>0;off>>=1) s+=__shfl_xor(s,off,32);
  float x21=e/s;
  int gc=bg*32+t;
  float is=istd[gc];
  av[gc]=x21*is*gnw[t];
  float cv=x21*(gnb[t]-mu[gc]*is*gnw[t]);
  for(int off=16;off>0;off>>=1) cv+=__shfl_xor(cv,off,32);
  if(t==0) cst[bg]=cv;
}

// K7X: pixel-major k7 using xt
__global__ __launch_bounds__(256) void k7x(const unsigned short* __restrict__ xt,
    const float* __restrict__ shT, const float* __restrict__ swT,
    const float* __restrict__ av, const float* __restrict__ binv, const float* __restrict__ cst,
    const float* __restrict__ w1a, float* __restrict__ sg1, float* __restrict__ s3pre){
  int bid = blockIdx.x; int b = bid/56, i = bid%56;
  __shared__ float shs[256], avs[256], bins[256], cst8[8];
  int tid = threadIdx.x;
  shs[tid]  = shT[((size_t)b*56+i)*256 + tid];
  avs[tid]  = av[b*256 + tid];
  bins[tid] = binv[tid];
  if(tid<8) cst8[tid] = cst[b*8+tid];
  __syncthreads();
  int h = tid>>5, l = tid&31;
  int bg = l>>2;
  int c0 = l*8;
  float sh8[8], av8[8], bi8[8];
  #pragma unroll
  for(int m=0;m<8;m++){ sh8[m]=shs[c0+m]; av8[m]=avs[c0+m]; bi8[m]=bins[c0+m]; }
  float cstv = cst8[bg];
  for(int pass=0; pass<7; ++pass){
    int j = pass*8 + h;
    short8 xv = *(const short8*)(xt + (((size_t)b*58 + i+1)*58 + j+1)*256 + c0);
    const float* swp = swT + ((size_t)b*56 + j)*256 + c0;
    float ws=0.f, s3=0.f;
    #pragma unroll
    for(int m=0;m<8;m++){
      float x0 = bf2f((unsigned short)xv[m]) * sh8[m] * swp[m];
      ws += av8[m]*x0;
      s3 += bi8[m]*x0;
    }
    ws += __shfl_xor(ws,1,64);
    ws += __shfl_xor(ws,2,64);
    s3 += __shfl_xor(s3,1,64);
    s3 += __shfl_xor(s3,2,64);
    s3 += __shfl_xor(s3,4,64);
    s3 += __shfl_xor(s3,8,64);
    s3 += __shfl_xor(s3,16,64);
    int p = i*56 + j;
    if((l&3)==0){
      size_t o = ((size_t)(b*8+bg))*HW + p;
      sg1[o] = sigmoidf_(w1a[o] + ws + cstv);
    }
    if(l==0) s3pre[(size_t)b*HW + p] = s3*(1.0f/256.0f);
  }
}

// softmax over HW per b, with input scale (1024 threads)
__global__ void k_softmax_hw(const float* __restrict__ in, float* __restrict__ out, float scale){
  int b=blockIdx.x;
  const float* ip=in+(size_t)b*HW;
  float mx=-1e30f;
  for(int p=threadIdx.x;p<HW;p+=blockDim.x) mx=fmaxf(mx,ip[p]*scale);
  for(int off=32;off>0;off>>=1) mx=fmaxf(mx,__shfl_xor(mx,off,64));
  __shared__ float red[16];
  int wid=threadIdx.x>>6, lane=threadIdx.x&63;
  int nw = blockDim.x>>6;
  if(lane==0) red[wid]=mx;
  __syncthreads();
  mx=red[0];
  for(int w=1;w<nw;w++) mx=fmaxf(mx,red[w]);
  float s=0.f;
  for(int p=threadIdx.x;p<HW;p+=blockDim.x) s+=__expf(ip[p]*scale-mx);
  for(int off=32;off>0;off>>=1) s+=__shfl_down(s,off,64);
  __shared__ float red2[16];
  if(lane==0) red2[wid]=s;
  __syncthreads();
  s=red2[0];
  for(int w=1;w<nw;w++) s+=red2[w];
  float inv=1.0f/s;
  for(int p=threadIdx.x;p<HW;p+=blockDim.x) out[(size_t)b*HW+p]=__expf(ip[p]*scale-mx)*inv;
}

// wt transform: wt[tap][oc][ic] = bf16(w3b[oc][ic][tap])
__global__ void kwt(const float* __restrict__ w3b, unsigned short* __restrict__ wt){
  int idx = blockIdx.x*256 + threadIdx.x;
  int tap = idx >> 16; int r = idx & 65535; int oc = r >> 8; int ic = r & 255;
  wt[idx] = f2bf(w3b[((size_t)oc*256 + ic)*9 + tap]);
}

// wta transform: wta[tap][oc][ic] = bf16(w3a[oc][ic][tap])
__global__ void kwta(const float* __restrict__ w3a, unsigned short* __restrict__ wta){
  int idx = blockIdx.x*256 + threadIdx.x;
  if(idx < 9216){
    int tap = idx >> 10; int r = idx & 1023; int oc = r >> 5; int ic = r & 31;
    wta[idx] = f2bf(w3a[((size_t)oc*32 + ic)*9 + tap]);
  }
}

// K9M: 256->256 3x3 conv via bf16 MFMA implicit GEMM, fused reductions.
// r12/r3 structure (per-(tap,chunk) staging, 72-step dbuf pipeline, VGPR ~56,
// conflict-free chunk-XOR swizzle) + XCD-aware bid swizzle. Proven 137 us.
__global__ __launch_bounds__(512) void k9m(const unsigned short* __restrict__ xt,
    const unsigned short* __restrict__ wt, const float* __restrict__ x31,
    float* __restrict__ s4pre, float* __restrict__ w2a){
  __shared__ short Ab[2][128*32];
  __shared__ short Bb[2][224*32];
  int bid = blockIdx.x;              // 896 = 8 xcd x 4 b x 28 rr
  int xcd = bid & 7; int idx = bid >> 3;
  int b = xcd + 8*(idx/28); int rr = idx % 28;
  int pt = rr >> 1; int oct = rr & 1;
  int i0 = pt*4; int ocb = oct*128;
  int tid = threadIdx.x;
  int lane = tid & 63, wv = tid >> 6;
  int wm = wv & 3, wn = wv >> 2;
  int q = lane >> 4, rl = lane & 15;
  const unsigned short* xb = xt + (size_t)b*58*58*256;

  #define STAGE_A(BUF, TAP, IC0) do{ \
    int idxl = tid; int oc_ = idxl>>2, cs_ = idxl&3; \
    const unsigned short* src = wt + (((size_t)(TAP)*256 + ocb + oc_)*256 + (IC0) + (((cs_ ^ ((oc_>>1)&3)))<<3)); \
    GLOAD16(src, &Ab[BUF][idxl*8]); }while(0)
  #define STAGE_B(BUF, TAP, IC0) do{ \
    int dy_ = (TAP)/3, dx_ = (TAP)%3; \
    { int idxl = tid; int px_ = idxl>>2, cs_ = idxl&3; int r_ = px_/56, j_ = px_ - r_*56; \
      const unsigned short* src = xb + ((size_t)((i0 + r_ + dy_)*58 + (j_ + dx_)))*256 + (IC0) + ((cs_ ^ ((px_>>1)&3))<<3); \
      GLOAD16(src, &Bb[BUF][idxl*8]); } \
    if(tid < 384){ int idxl = tid + 512; int px_ = idxl>>2, cs_ = idxl&3; int r_ = px_/56, j_ = px_ - r_*56; \
      const unsigned short* src = xb + ((size_t)((i0 + r_ + dy_)*58 + (j_ + dx_)))*256 + (IC0) + ((cs_ ^ ((px_>>1)&3))<<3); \
      GLOAD16(src, &Bb[BUF][idxl*8]); } }while(0)

  STAGE_A(0, 0, 0);
  STAGE_B(0, 0, 0);
  __syncthreads();

  f32x4 acc[2][7];
  #pragma unroll
  for(int mi=0;mi<2;mi++)
    #pragma unroll
    for(int ni=0;ni<7;ni++) acc[mi][ni] = (f32x4){0.f,0.f,0.f,0.f};

  for(int t=0; t<72; ++t){
    int cur = t & 1;
    if(t+1 < 72){
      int tn = t+1; int tap = tn >> 3; int ic0 = (tn & 7) << 5;
      STAGE_A(cur^1, tap, ic0);
      STAGE_B(cur^1, tap, ic0);
    }
    short8 a[2], bf[7];
    #pragma unroll
    for(int mi=0;mi<2;mi++){
      int row = wm*32 + mi*16 + rl;
      int cs = q ^ ((row>>1)&3);
      a[mi] = *(const short8*)&Ab[cur][row*32 + cs*8];
    }
    #pragma unroll
    for(int ni=0;ni<7;ni++){
      int px = wn*112 + ni*16 + rl;
      int cs = q ^ ((px>>1)&3);
      bf[ni] = *(const short8*)&Bb[cur][px*32 + cs*8];
    }
    #pragma unroll
    for(int mi=0;mi<2;mi++)
      #pragma unroll
      for(int ni=0;ni<7;ni++)
        acc[mi][ni] = __builtin_amdgcn_mfma_f32_16x16x32_bf16(a[mi], bf[ni], acc[mi][ni], 0,0,0);
    __syncthreads();
  }
  #undef STAGE_A
  #undef STAGE_B

  size_t pxbase = (size_t)b*HW + i0*56 + wn*112;
  #pragma unroll
  for(int ni=0;ni<7;ni++){
    float s = 0.f;
    #pragma unroll
    for(int mi=0;mi<2;mi++){
      s += acc[mi][ni][0]+acc[mi][ni][1]+acc[mi][ni][2]+acc[mi][ni][3];
    }
    s += __shfl_xor(s, 16, 64);
    s += __shfl_xor(s, 32, 64);
    if(lane < 16) atomicAdd(&s4pre[pxbase + ni*16 + lane], s);
  }
  float x31v[7];
  #pragma unroll
  for(int ni=0;ni<7;ni++) x31v[ni] = x31[pxbase + ni*16 + rl];
  #pragma unroll
  for(int mi=0;mi<2;mi++){
    #pragma unroll
    for(int r=0;r<4;r++){
      float s = 0.f;
      #pragma unroll
      for(int ni=0;ni<7;ni++) s += x31v[ni]*acc[mi][ni][r];
      s += __shfl_xor(s, 1, 64);
      s += __shfl_xor(s, 2, 64);
      s += __shfl_xor(s, 4, 64);
      s += __shfl_xor(s, 8, 64);
      if(rl == 0) atomicAdd(&w2a[b*256 + ocb + wm*32 + mi*16 + q*4 + r], s);
    }
  }
}

// K11F: fused k11+k12.
__global__ __launch_bounds__(256) void k11f(const float* __restrict__ x, const float* __restrict__ sh,
    const float* __restrict__ sw, const float* __restrict__ x41, const float* __restrict__ bm,
    const float* __restrict__ binv, const float* __restrict__ w2a, const float* __restrict__ b3b,
    const float* __restrict__ sg1, float* __restrict__ out){
  int gc=blockIdx.x; int b=gc>>8, c=gc&255, bg=gc>>5;
  __shared__ float xs[HW];
  __shared__ float ssh[56], ssw[56];
  __shared__ float red[4];
  int tid=threadIdx.x;
  if(tid<56) ssh[tid]=sh[gc*56+tid];
  else if(tid>=64&&tid<120) ssw[tid-64]=sw[gc*56+tid-64];
  const float* xp=x+(size_t)gc*HW;
  const float* wp=x41+(size_t)b*HW;
  for(int p=tid;p<HW;p+=256) xs[p]=xp[p];
  __syncthreads();
  float s=0.f;
  for(int p=tid;p<HW;p+=256){
    float x0=xs[p]*ssh[p/56]*ssw[p%56];
    s+=wp[p]*x0;
  }
  for(int off=32;off>0;off>>=1) s+=__shfl_down(s,off,64);
  int wid=tid>>6, lane=tid&63;
  if(lane==0) red[wid]=s;
  __syncthreads();
  float t=red[0]+red[1]+red[2]+red[3];
  float sg2=sigmoidf_(w2a[gc]+b3b[c]+binv[c]*t-bm[c]*binv[c]);
  const float* sp=sg1+(size_t)bg*HW;
  float* op=out+(size_t)gc*HW;
  for(int p=tid;p<HW;p+=256){
    op[p]=xs[p]*(sp[p]+sg2);
  }
}

extern "C" void kernel_launch(void* const* d_in, const int* in_sizes, int n_in,
                              void* d_out, int out_size, void* d_ws, size_t ws_size,
                              hipStream_t stream) {
  const float* x   = (const float*)d_in[0];
  const float* w1  = (const float*)d_in[1];
  const float* b1  = (const float*)d_in[2];
  const float* w3a = (const float*)d_in[3];
  const float* b3a = (const float*)d_in[4];
  const float* w3b = (const float*)d_in[5];
  const float* b3b = (const float*)d_in[6];
  const float* gnw = (const float*)d_in[7];
  const float* gnb = (const float*)d_in[8];
  float* out=(float*)d_out;
  float* ws=(float*)d_ws;

  float* rowm=ws;              // 458752
  float* colm=rowm+458752;     // 458752
  float* sh  =colm+458752;     // 458752
  float* sw  =sh+458752;       // 458752
  float* x11 =sw+458752;       // 64 (33 used)
  float* gsum=x11+64;          // 8192
  float* gsq =gsum+8192;       // 8192
  float* mu  =gsq+8192;        // 8192
  float* istd=mu+8192;         // 8192
  float* bm  =istd+8192;       // 256
  float* binv=bm+256;          // 256
  float* cs2 =binv+256;        // 8192
  float* w1a =cs2+8192;        // 802816
  float* av  =w1a+802816;      // 8192
  float* cst =av+8192;         // 256
  float* s3  =cst+256;         // 100352
  float* x31 =s3+100352;       // 100352
  float* s4  =x31+100352;      // 100352
  float* x41 =s4+100352;       // 100352
  float* w2a =x41+100352;      // 8192
  float* shT =w2a+8192;        // 458752
  float* swT =shT+458752;      // 458752
  float* sg1 =swT+458752;      // 802816 (sigmoid(weights1))
  unsigned short* xt = (unsigned short*)(sg1 + 802816);  // 32*58*58*256 bf16
  unsigned short* wtb = xt + (size_t)32*58*58*256;       // 589824
  unsigned short* wta = wtb + 589824;                    // 9216

  kxt<<<32*4*49,256,0,stream>>>(x, xt);
  khalo<<<32*228,256,0,stream>>>(xt);
  kwt<<<2304,256,0,stream>>>(w3b, wtb);
  kwta<<<36,256,0,stream>>>(w3a, wta);

  k1t<<<32*112,256,0,stream>>>(xt,rowm,colm);
  k2_hw<<<BG,128,0,stream>>>(rowm,colm,w1,b1,sh,sw,shT,swT);
  k2b_x11<<<1,32,0,stream>>>(gnb,b3a,x11);
  hipMemsetAsync(gsum,0,2*8192*sizeof(float),stream);
  k3t<<<32*56,256,0,stream>>>(xt,shT,swT,gsum,gsq);
  k4a<<<32,256,0,stream>>>(gsum,gsq,mu,istd);
  k4b<<<1,256,0,stream>>>(gsum,gsq,bm,binv);
  hipMemsetAsync(cs2,0,8192*sizeof(float),stream);
  k5m<<<256*14,128,0,stream>>>(xt,wta,x11,w1a,cs2);
  k6<<<BG,32,0,stream>>>(cs2,b3a,mu,istd,gnw,gnb,av,cst);
  k7x<<<B*56,256,0,stream>>>(xt,shT,swT,av,binv,cst,w1a,sg1,s3);
  k_softmax_hw<<<B,1024,0,stream>>>(s3,x31,1.0f);
  hipMemsetAsync(w2a,0,8192*sizeof(float),stream);
  hipMemsetAsync(s4,0,(size_t)HW*B*sizeof(float),stream);
  k9m<<<32*28,512,0,stream>>>(xt,wtb,x31,s4,w2a);
  k_softmax_hw<<<B,1024,0,stream>>>(s4,x41,1.0f/256.0f);
  k11f<<<GC,256,0,stream>>>(x,sh,sw,x41,bm,binv,w2a,b3b,sg1,out);
}